// Round 12
// baseline (526.794 us; speedup 1.0000x reference)
//
#include <hip/hip_runtime.h>
#include <hip/hip_fp16.h>

// Regrid: sequential-stream staged gather + LLC-random reduce.
// y[n, b] = sum_{k: rows[k]==b} w[k] * x[n, flip(cols[k])]
// x: (140, 721*1440) f32, rows/cols: (260640,) i32, w: f32, out: (140, 181*360) f32.
//
// Preproc (r9's proven chain): window(512-float) hist + row hist -> 2-block
// scan -> permute: perm[j_cf] = (cf, w_bits) window-sorted; jlist[j_row] = j_cf.
// Gather: block = one 512-float x-window; loops 140 planes, staging its 2KB
// window slice per plane into LDS (dbuf, sequential float2 loads -> machine
// sweeps x as a sharded memcpy: DRAM page hits, no 900cy random-miss MSHR
// bound), serves its ~128 nnz from LDS, packs 70 fp16 pairs in VGPRs
// (~90 VGPR, no spill - r8's fatal flaw fixed), writes 288B g row at j_cf
// (block-contiguous, fully sequential stream). Reduce: per row b, jlist gives
// g rows; random 288B reads hit the LLC-resident g (75MB << 256MB), f32
// accumulate, LDS transpose, coalesced out. No global atomics in hot phases;
// d_out fully overwritten -> no zeroing.

#define NXS 1440
#define NYS 721
#define N_A_CONST (721 * 1440)
#define N_B_CONST (181 * 360)
#define WFL2 512                          // window floats (2KB)
#define NW2 ((N_A_CONST + WFL2 - 1) / WFL2)   // 2028 windows
#define NFIELD 140
#define NPAIR (NFIELD / 2)                // 70 packed fp16 pairs
#define GDW 72                            // g row stride in dwords (288B)

__device__ __forceinline__ int flip_col(int c) {
    int iy = c / NXS;
    int ix = c - iy * NXS;
    return (NYS - 1 - iy) * NXS + ix;
}

// ---------- preprocessing (r9 structure) ----------

__global__ void zero_ws_kernel(int* __restrict__ p, int n) {
    int i = blockIdx.x * blockDim.x + threadIdx.x;
    int stride = gridDim.x * blockDim.x;
    for (; i < n; i += stride) p[i] = 0;
}

__global__ void hist2_kernel(const int* __restrict__ rows, const int* __restrict__ cols,
                             int* __restrict__ wcount, int* __restrict__ rcount, int nnz) {
    int k = blockIdx.x * blockDim.x + threadIdx.x;
    if (k >= nnz) return;
    int cf = flip_col(cols[k]);
    atomicAdd(&wcount[cf >> 9], 1);
    atomicAdd(&rcount[rows[k]], 1);
}

// block 0: wcount->woff (NW2); block 1: rcount->roff (N_B). 1024 thr x 64 elems.
__global__ void scan2_kernel(const int* __restrict__ wcount, int* __restrict__ woff,
                             const int* __restrict__ rcount, int* __restrict__ roff) {
    const int* in; int* out; int n;
    if (blockIdx.x == 0) { in = wcount; out = woff; n = NW2; }
    else                 { in = rcount; out = roff; n = N_B_CONST; }

    int t = threadIdx.x;
    int base = t * 64;
    int s = 0;
    for (int i = 0; i < 64; ++i) {
        int idx = base + i;
        s += (idx < n) ? in[idx] : 0;
    }
    int lane = t & 63;
    int wv = t >> 6;
    int incl = s;
    #pragma unroll
    for (int off = 1; off < 64; off <<= 1) {
        int u = __shfl_up(incl, off, 64);
        if (lane >= off) incl += u;
    }
    __shared__ int wsum[16];
    if (lane == 63) wsum[wv] = incl;
    __syncthreads();
    if (t < 16) {
        int v = wsum[t];
        #pragma unroll
        for (int off = 1; off < 16; off <<= 1) {
            int u = __shfl_up(v, off, 16);
            if (t >= off) v += u;
        }
        wsum[t] = v;
    }
    __syncthreads();
    int waveoff = (wv == 0) ? 0 : wsum[wv - 1];
    int run = waveoff + incl - s;
    for (int i = 0; i < 64; ++i) {
        int idx = base + i;
        if (idx < n) { out[idx] = run; run += in[idx]; }
    }
    if (t == 1023) out[n] = run;
}

// perm[j_cf] = (cf, w_bits); jlist[j_row] = j_cf.
__global__ void perm2_kernel(const int* __restrict__ rows, const int* __restrict__ cols,
                             const float* __restrict__ w,
                             const int* __restrict__ woff, int* __restrict__ wcur,
                             const int* __restrict__ roff, int* __restrict__ rcur,
                             int2* __restrict__ perm, int* __restrict__ jlist, int nnz) {
    int k = blockIdx.x * blockDim.x + threadIdx.x;
    if (k >= nnz) return;
    int cf = flip_col(cols[k]);
    int wu = cf >> 9;
    int j_cf = woff[wu] + atomicAdd(&wcur[wu], 1);
    int b = rows[k];
    int j_row = roff[b] + atomicAdd(&rcur[b], 1);
    perm[j_cf] = make_int2(cf, __float_as_int(w[k]));
    jlist[j_row] = j_cf;
}

// ---------- hot phases ----------

// Block = one 512-float window; 140-plane loop with LDS double-buffer.
__global__ void gather_staged_kernel(const float* __restrict__ x,
                                     const int2* __restrict__ perm,
                                     const int* __restrict__ woff,
                                     unsigned int* __restrict__ g, int nnz) {
    __shared__ float sbuf[2][WFL2];
    int wx = blockIdx.x;
    int base = wx * WFL2;
    int lim = N_A_CONST - base; if (lim > WFL2) lim = WFL2;
    int tid = threadIdx.x;
    int j0 = woff[wx], j1 = woff[wx + 1];
    int count = j1 - j0;
    if (count == 0) return;                 // block-uniform

    bool act = tid < count;
    int2 p = perm[act ? (j0 + tid) : j0];
    int cfl = p.x - base;
    float wj = __int_as_float(p.y);
    unsigned int v[NPAIR];

    int i2 = 2 * tid;
    bool ldok = i2 < lim;
    const float* xw = x + base + i2;

    // prologue: stage plane 0, load plane 1
    float2 r = ldok ? *(const float2*)&xw[0] : make_float2(0.f, 0.f);
    *(float2*)&sbuf[0][i2] = r;
    r = ldok ? *(const float2*)&xw[(size_t)1 * N_A_CONST] : make_float2(0.f, 0.f);
    __syncthreads();

    float prevf = 0.f;
    for (int c = 0; c < NFIELD; ++c) {
        float2 rn;
        if (c + 2 < NFIELD)
            rn = ldok ? *(const float2*)&xw[(size_t)(c + 2) * N_A_CONST]
                      : make_float2(0.f, 0.f);
        float f = sbuf[c & 1][cfl];
        if (c & 1) {
            unsigned int lo = __half_as_ushort(__float2half(wj * prevf));
            unsigned int hi = __half_as_ushort(__float2half(wj * f));
            v[c >> 1] = lo | (hi << 16);
        } else {
            prevf = f;
        }
        if (c + 1 < NFIELD) {
            *(float2*)&sbuf[(c + 1) & 1][i2] = r;   // write next plane (vmcnt wait)
            r = rn;
        }
        __syncthreads();
    }

    if (act) {
        unsigned int* gr = g + (size_t)(j0 + tid) * GDW;   // SEQUENTIAL write
        #pragma unroll
        for (int i = 0; i < 17; ++i)
            *(uint4*)(gr + 4 * i) = make_uint4(v[4 * i], v[4 * i + 1],
                                               v[4 * i + 2], v[4 * i + 3]);
        *(uint2*)(gr + 68) = make_uint2(v[68], v[69]);
    }

    // overflow slow path (count > 256): statistically never taken (lambda~128)
    if (count > 256) {
        for (int jj = j0 + 256 + tid; jj < j1; jj += 256) {
            int2 q = perm[jj];
            const float* xp = x + q.x;
            float qw = __int_as_float(q.y);
            #pragma unroll
            for (int pp = 0; pp < NPAIR; ++pp) {
                float f0 = xp[(size_t)(2 * pp) * N_A_CONST];
                float f1 = xp[(size_t)(2 * pp + 1) * N_A_CONST];
                v[pp] = __half_as_ushort(__float2half(qw * f0)) |
                        ((unsigned int)__half_as_ushort(__float2half(qw * f1)) << 16);
            }
            unsigned int* gr = g + (size_t)jj * GDW;
            #pragma unroll
            for (int i = 0; i < 17; ++i)
                *(uint4*)(gr + 4 * i) = make_uint4(v[4 * i], v[4 * i + 1],
                                                   v[4 * i + 2], v[4 * i + 3]);
            *(uint2*)(gr + 68) = make_uint2(v[68], v[69]);
        }
    }
}

__device__ __forceinline__ float h2f_lo(unsigned int d) {
    return __half2float(__ushort_as_half((unsigned short)(d & 0xffffu)));
}
__device__ __forceinline__ float h2f_hi(unsigned int d) {
    return __half2float(__ushort_as_half((unsigned short)(d >> 16)));
}

// Block = 64 rows; g rows located via jlist (random 288B reads, LLC-resident g).
__global__ __launch_bounds__(256)
void reduce_kernel(const unsigned int* __restrict__ g, const int* __restrict__ jlist,
                   const int* __restrict__ roff, float* __restrict__ out) {
    __shared__ float lds[64][141];
    int b0 = blockIdx.x * 64;
    int lane = threadIdx.x & 63;
    int wv = threadIdx.x >> 6;

    for (int i = 0; i < 16; ++i) {
        int bl = wv * 16 + i;
        int b = b0 + bl;
        if (b < N_B_CONST) {
            int p0 = roff[b], p1 = roff[b + 1];
            float a0 = 0.f, a1 = 0.f, a2 = 0.f, a3 = 0.f;
            for (int pos = p0; pos < p1; ++pos) {
                int j = jlist[pos];
                const unsigned int* gr = g + (size_t)j * GDW;
                unsigned int d = gr[lane];
                a0 += h2f_lo(d); a1 += h2f_hi(d);
                if (lane < 6) {
                    unsigned int e = gr[64 + lane];
                    a2 += h2f_lo(e); a3 += h2f_hi(e);
                }
            }
            lds[bl][2 * lane]     = a0;
            lds[bl][2 * lane + 1] = a1;
            if (lane < 6) {
                lds[bl][128 + 2 * lane] = a2;
                lds[bl][129 + 2 * lane] = a3;
            }
        }
    }
    __syncthreads();

    int nb = N_B_CONST - b0; if (nb > 64) nb = 64;
    for (int idx = threadIdx.x; idx < NFIELD * 64; idx += 256) {
        int f = idx >> 6;
        int rr = idx & 63;
        if (rr < nb)
            out[(size_t)f * N_B_CONST + b0 + rr] = lds[rr][f];
    }
}

// ---------- fallback ----------

__global__ void zero_out_kernel(float* __restrict__ out, int n) {
    int i = blockIdx.x * blockDim.x + threadIdx.x;
    int stride = gridDim.x * blockDim.x;
    for (; i < n; i += stride) out[i] = 0.0f;
}

__global__ void scatter_fallback_kernel(const float* __restrict__ x, const int* __restrict__ rows,
                                        const int* __restrict__ cols, const float* __restrict__ w,
                                        float* __restrict__ out, int nnz) {
    int k = blockIdx.x * blockDim.x + threadIdx.x;
    if (k >= nnz) return;
    int n = blockIdx.y;
    int cf = flip_col(cols[k]);
    float v = w[k] * x[(size_t)n * N_A_CONST + cf];
    atomicAdd(out + (size_t)n * N_B_CONST + rows[k], v);
}

extern "C" void kernel_launch(void* const* d_in, const int* in_sizes, int n_in,
                              void* d_out, int out_size, void* d_ws, size_t ws_size,
                              hipStream_t stream) {
    const float* x    = (const float*)d_in[0];
    const int*   rows = (const int*)d_in[1];
    const int*   cols = (const int*)d_in[2];
    const float* w    = (const float*)d_in[3];
    float* out = (float*)d_out;

    int nnz    = in_sizes[1];
    int nfield = in_sizes[0] / N_A_CONST;   // 140

    // ws layout (int units). Count/cursor arrays first: zeroed by one kernel.
    size_t o = 0;
    size_t wcount_o = o; o += NW2;
    size_t wcur_o   = o; o += NW2;
    size_t rcount_o = o; o += N_B_CONST;
    size_t rcur_o   = o; o += N_B_CONST;
    size_t zero_span = o;
    size_t woff_o   = o; o += NW2 + 1;
    size_t roff_o   = o; o += N_B_CONST + 1;
    o = (o + 31) & ~(size_t)31;                 // 128B-align perm
    size_t perm_o   = o; o += 2 * (size_t)nnz;  // int2
    size_t jlist_o  = o; o += nnz;
    o = (o + 31) & ~(size_t)31;                 // 128B-align g
    size_t g_o      = o;
    size_t need_bytes = (g_o + (size_t)nnz * GDW) * sizeof(int);

    if (ws_size < need_bytes || nfield != NFIELD) {
        zero_out_kernel<<<2048, 256, 0, stream>>>(out, out_size);
        dim3 grid((nnz + 255) / 256, nfield);
        scatter_fallback_kernel<<<grid, 256, 0, stream>>>(x, rows, cols, w, out, nnz);
        return;
    }

    int*  wsI    = (int*)d_ws;
    int*  wcount = wsI + wcount_o;
    int*  wcur   = wsI + wcur_o;
    int*  rcount = wsI + rcount_o;
    int*  rcur   = wsI + rcur_o;
    int*  woff   = wsI + woff_o;
    int*  roff   = wsI + roff_o;
    int2* perm   = (int2*)(wsI + perm_o);
    int*  jlist  = wsI + jlist_o;
    unsigned int* g = (unsigned int*)(wsI + g_o);

    zero_ws_kernel<<<512, 256, 0, stream>>>(wsI, (int)zero_span);

    int nblk = (nnz + 255) / 256;   // 1019
    hist2_kernel<<<nblk, 256, 0, stream>>>(rows, cols, wcount, rcount, nnz);
    scan2_kernel<<<2, 1024, 0, stream>>>(wcount, woff, rcount, roff);
    perm2_kernel<<<nblk, 256, 0, stream>>>(rows, cols, w, woff, wcur, roff, rcur,
                                           perm, jlist, nnz);

    gather_staged_kernel<<<NW2, 256, 0, stream>>>(x, perm, woff, g, nnz);

    int rblk = (N_B_CONST + 63) / 64;   // 1019
    reduce_kernel<<<rblk, 256, 0, stream>>>(g, jlist, roff, out);
}